// Round 2
// baseline (1077.057 us; speedup 1.0000x reference)
//
#include <hip/hip_runtime.h>

static constexpr int B_ = 64;
static constexpr int N_ = 4096;
static constexpr int V_ = 21;
static constexpr int S_ = 50;
static constexpr int E_ = 64;
static constexpr int H_ = 128;

union F4 { float4 v; float f[4]; };

__device__ __forceinline__ float sigm(float x) { return 1.0f / (1.0f + __expf(-x)); }
__device__ __forceinline__ float tanh_(float x) {
  float a = fabsf(x);
  float e = __expf(-2.0f * a);
  float t = (1.0f - e) / (1.0f + e);
  return x < 0.0f ? -t : t;
}

// ---- precompute: transpose U weights into k-major [128][512] (cols: Ui|Uo|Uu|Uf) ----
__global__ void k_transpose(const float* __restrict__ Ui, const float* __restrict__ Uo,
                            const float* __restrict__ Uu, const float* __restrict__ Uf,
                            float* __restrict__ Wt) {
  int idx = blockIdx.x * 256 + threadIdx.x;
  if (idx >= 128 * 512) return;
  int k = idx >> 9, col = idx & 511;
  int g = col >> 7, o = col & 127;
  const float* U = (g == 0) ? Ui : (g == 1) ? Uo : (g == 2) ? Uu : Uf;
  Wt[idx] = U[o * 128 + k];
}

// ---- precompute: leaf h/c tables, one block per vocab id ----
__global__ void k_leaf(const float* __restrict__ emb, const float* __restrict__ Wp, const float* __restrict__ bp,
                       const float* __restrict__ Wi, const float* __restrict__ bi,
                       const float* __restrict__ Wo, const float* __restrict__ bo,
                       const float* __restrict__ Wu, const float* __restrict__ bu,
                       float* __restrict__ leaf_h, float* __restrict__ leaf_c) {
  int v = blockIdx.x, o = threadIdx.x;
  __shared__ float x[128];
  float acc = bp[o];
  if (v != 0) {  // reference zeroes emb row 0
    for (int e = 0; e < E_; ++e) acc = fmaf(emb[v * E_ + e], Wp[o * E_ + e], acc);
  }
  x[o] = acc;
  __syncthreads();
  float zi = bi[o], zo = bo[o], zu = bu[o];
  for (int k = 0; k < H_; ++k) {
    float xv = x[k];
    zi = fmaf(xv, Wi[o * H_ + k], zi);
    zo = fmaf(xv, Wo[o * H_ + k], zo);
    zu = fmaf(xv, Wu[o * H_ + k], zu);
  }
  float gi = sigm(zi), go = sigm(zo), gu = tanh_(zu);
  float c = gi * gu;
  leaf_c[v * H_ + o] = c;
  leaf_h[v * H_ + o] = go * tanh_(c);
}

// ---- precompute: per-symbol x-side gate pre-activations [S][4][128] (i,o,u,f) ----
__global__ void k_sym(const float* __restrict__ sym_emb, const float* __restrict__ Wp, const float* __restrict__ bp,
                      const float* __restrict__ Wi, const float* __restrict__ bi,
                      const float* __restrict__ Wo, const float* __restrict__ bo,
                      const float* __restrict__ Wu, const float* __restrict__ bu,
                      const float* __restrict__ Wf, const float* __restrict__ bf,
                      float* __restrict__ symx) {
  int s = blockIdx.x, o = threadIdx.x;
  __shared__ float x[128];
  float acc = bp[o];
  for (int e = 0; e < E_; ++e) acc = fmaf(sym_emb[s * E_ + e], Wp[o * E_ + e], acc);
  x[o] = acc;
  __syncthreads();
  float zi = bi[o], zo = bo[o], zu = bu[o], zf = bf[o];
  for (int k = 0; k < H_; ++k) {
    float xv = x[k];
    zi = fmaf(xv, Wi[o * H_ + k], zi);
    zo = fmaf(xv, Wo[o * H_ + k], zo);
    zu = fmaf(xv, Wu[o * H_ + k], zu);
    zf = fmaf(xv, Wf[o * H_ + k], zf);
  }
  size_t base = (size_t)s * 4 * H_;
  symx[base + 0 * H_ + o] = zi;
  symx[base + 1 * H_ + o] = zo;
  symx[base + 2 * H_ + o] = zu;
  symx[base + 3 * H_ + o] = zf;
}

// ---- one tree level: 32 nodes/block, 256 threads, 5 fused matvecs + gates ----
template <bool LEAF>
__global__ void __launch_bounds__(256, 2) k_level(
    const float* __restrict__ Wt, const float* __restrict__ symx,
    const int* __restrict__ symbols, int sym_off, int lgm,
    const float* __restrict__ h_prev, const float* __restrict__ c_prev,
    const int* __restrict__ tokens,
    const float* __restrict__ leaf_h, const float* __restrict__ leaf_c,
    float* __restrict__ h_out, float* __restrict__ c_out) {
  __shared__ float P[64][128];   // children h rows: node jj -> rows 2jj, 2jj+1
  __shared__ float WL[16][512];  // weight k-chunk
  int t = threadIdx.x;
  int to = t & 31, tn = t >> 5;  // to: output group (4*to..), tn: node group (4*tn..)
  int g0 = blockIdx.x * 32;

  // stage children h (64 rows x 128) into LDS — coalesced float4
  #pragma unroll
  for (int i = 0; i < 8; ++i) {
    int fid = t + 256 * i;
    int row = fid >> 5;
    int c4 = (fid & 31) << 2;
    const float* src;
    if (LEAF) {
      int tok = tokens[2 * g0 + row];
      src = leaf_h + tok * H_ + c4;
    } else {
      src = h_prev + (size_t)(2 * g0 + row) * H_ + c4;
    }
    *(float4*)&P[row][c4] = *(const float4*)src;
  }
  __syncthreads();

  float ai[4][4] = {}, ao[4][4] = {}, au[4][4] = {}, afl[4][4] = {}, afr[4][4] = {};

  for (int kc = 0; kc < 8; ++kc) {
    if (kc) __syncthreads();
    #pragma unroll
    for (int i = 0; i < 8; ++i) {
      int fid = t + 256 * i;
      int kr = fid >> 7;
      int c4 = (fid & 127) << 2;
      *(float4*)&WL[kr][c4] = *(const float4*)(Wt + (size_t)(kc * 16 + kr) * 512 + c4);
    }
    __syncthreads();
    #pragma unroll
    for (int kk = 0; kk < 16; ++kk) {
      F4 bi4, bo4, bu4, bf4;
      bi4.v = *(float4*)&WL[kk][0 + 4 * to];
      bo4.v = *(float4*)&WL[kk][128 + 4 * to];
      bu4.v = *(float4*)&WL[kk][256 + 4 * to];
      bf4.v = *(float4*)&WL[kk][384 + 4 * to];
      int kg = kc * 16 + kk;
      #pragma unroll
      for (int n = 0; n < 4; ++n) {
        float hl = P[8 * tn + 2 * n][kg];
        float hr = P[8 * tn + 2 * n + 1][kg];
        float ht = hl + hr;
        #pragma unroll
        for (int q = 0; q < 4; ++q) {
          ai[n][q] = fmaf(ht, bi4.f[q], ai[n][q]);
          ao[n][q] = fmaf(ht, bo4.f[q], ao[n][q]);
          au[n][q] = fmaf(ht, bu4.f[q], au[n][q]);
          afl[n][q] = fmaf(hl, bf4.f[q], afl[n][q]);
          afr[n][q] = fmaf(hr, bf4.f[q], afr[n][q]);
        }
      }
    }
  }

  // epilogue: gates + c/h combine, coalesced float4 stores
  int m_mask = (1 << lgm) - 1;
  #pragma unroll
  for (int n = 0; n < 4; ++n) {
    int jj = 4 * tn + n;
    int g = g0 + jj;
    int b = g >> lgm;
    int j = g & m_mask;
    int s = symbols[b * (N_ - 1) + sym_off + j];
    const float* sx = symx + (size_t)s * 4 * H_;
    int o0 = 4 * to;
    F4 sxi, sxo, sxu, sxf, cl4, cr4;
    sxi.v = *(const float4*)(sx + 0 * H_ + o0);
    sxo.v = *(const float4*)(sx + 1 * H_ + o0);
    sxu.v = *(const float4*)(sx + 2 * H_ + o0);
    sxf.v = *(const float4*)(sx + 3 * H_ + o0);
    if (LEAF) {
      int tl = tokens[2 * g], tr = tokens[2 * g + 1];
      cl4.v = *(const float4*)(leaf_c + tl * H_ + o0);
      cr4.v = *(const float4*)(leaf_c + tr * H_ + o0);
    } else {
      cl4.v = *(const float4*)(c_prev + (size_t)(2 * g) * H_ + o0);
      cr4.v = *(const float4*)(c_prev + (size_t)(2 * g + 1) * H_ + o0);
    }
    F4 hq, cq;
    #pragma unroll
    for (int q = 0; q < 4; ++q) {
      float gi = sigm(sxi.f[q] + ai[n][q]);
      float go = sigm(sxo.f[q] + ao[n][q]);
      float gu = tanh_(sxu.f[q] + au[n][q]);
      float fl = sigm(sxf.f[q] + afl[n][q]);
      float fr = sigm(sxf.f[q] + afr[n][q]);
      float cv = fmaf(gi, gu, fmaf(fl, cl4.f[q], fr * cr4.f[q]));
      cq.f[q] = cv;
      hq.f[q] = go * tanh_(cv);
    }
    *(float4*)(h_out + (size_t)g * H_ + o0) = hq.v;
    *(float4*)(c_out + (size_t)g * H_ + o0) = cq.v;
  }
}

// ---- final projection: out = root_h @ Wout.T + bout ----
__global__ void k_out(const float* __restrict__ hroot, const float* __restrict__ Wout,
                      const float* __restrict__ bout, float* __restrict__ out) {
  int b = blockIdx.x, o = threadIdx.x;
  __shared__ float hr[128];
  hr[o] = hroot[(size_t)b * H_ + o];
  __syncthreads();
  float acc = bout[o];
  for (int k = 0; k < H_; ++k) acc = fmaf(hr[k], Wout[o * H_ + k], acc);
  out[(size_t)b * H_ + o] = acc;
}

extern "C" void kernel_launch(void* const* d_in, const int* in_sizes, int n_in,
                              void* d_out, int out_size, void* d_ws, size_t ws_size,
                              hipStream_t stream) {
  const int* tokens   = (const int*)d_in[0];
  const int* symbols  = (const int*)d_in[1];
  const float* emb    = (const float*)d_in[2];
  const float* sym_emb= (const float*)d_in[3];
  const float* Wp  = (const float*)d_in[4];
  const float* bp  = (const float*)d_in[5];
  const float* Wi  = (const float*)d_in[6];
  const float* bi  = (const float*)d_in[7];
  const float* Ui  = (const float*)d_in[8];
  const float* Wf  = (const float*)d_in[9];
  const float* bf  = (const float*)d_in[10];
  const float* Uf  = (const float*)d_in[11];
  const float* Wo  = (const float*)d_in[12];
  const float* bo  = (const float*)d_in[13];
  const float* Uo  = (const float*)d_in[14];
  const float* Wu  = (const float*)d_in[15];
  const float* bu  = (const float*)d_in[16];
  const float* Uu  = (const float*)d_in[17];
  const float* Wout= (const float*)d_in[18];
  const float* bout= (const float*)d_in[19];

  // Workspace layout (ping-pong: A holds odd-level outputs, B even-level).
  // Total = 386,048 + 2*67,108,864 + 2*33,554,432 = 201,712,640 bytes.
  char* ws = (char*)d_ws;
  float* Wt     = (float*)(ws);                        // 262144 B
  float* leaf_h = (float*)(ws + 262144);               // 10752 B
  float* leaf_c = (float*)(ws + 272896);               // 10752 B
  float* symx   = (float*)(ws + 283648);               // 102400 B
  float* A_h    = (float*)(ws + 386048);                          // 64*2048*128*4 = 67108864 B
  float* A_c    = (float*)(ws + 386048 + 67108864UL);             // 67108864 B
  float* B_h    = (float*)(ws + 386048 + 134217728UL);            // 64*1024*128*4 = 33554432 B
  float* B_c    = (float*)(ws + 386048 + 167772160UL);            // 33554432 B

  k_transpose<<<256, 256, 0, stream>>>(Ui, Uo, Uu, Uf, Wt);
  k_leaf<<<V_, 128, 0, stream>>>(emb, Wp, bp, Wi, bi, Wo, bo, Wu, bu, leaf_h, leaf_c);
  k_sym<<<S_, 128, 0, stream>>>(sym_emb, Wp, bp, Wi, bi, Wo, bo, Wu, bu, Wf, bf, symx);

  float* prev_h = nullptr;
  float* prev_c = nullptr;
  int off = 0;
  for (int l = 1; l <= 12; ++l) {
    int m = N_ >> l;
    int M = B_ * m;
    int lgm = 12 - l;
    float* oh = (l & 1) ? A_h : B_h;
    float* oc = (l & 1) ? A_c : B_c;
    if (l == 1) {
      k_level<true><<<M / 32, 256, 0, stream>>>(Wt, symx, symbols, off, lgm,
          nullptr, nullptr, tokens, leaf_h, leaf_c, oh, oc);
    } else {
      k_level<false><<<M / 32, 256, 0, stream>>>(Wt, symx, symbols, off, lgm,
          prev_h, prev_c, nullptr, nullptr, nullptr, oh, oc);
    }
    prev_h = oh;
    prev_c = oc;
    off += m;
  }
  k_out<<<B_, 128, 0, stream>>>(prev_h, Wout, bout, (float*)d_out);
}

// Round 3
// 347.154 us; speedup vs baseline: 3.1025x; 3.1025x over previous
//
#include <hip/hip_runtime.h>
#include <hip/hip_bf16.h>

typedef __attribute__((ext_vector_type(8))) short short8;
typedef __attribute__((ext_vector_type(4))) float f32x4;

static constexpr int B_ = 64;
static constexpr int N_ = 4096;
static constexpr int V_ = 21;
static constexpr int S_ = 50;
static constexpr int E_ = 64;
static constexpr int H_ = 128;

__device__ __forceinline__ float sigm(float x) { return 1.0f / (1.0f + __expf(-x)); }
__device__ __forceinline__ float tanh_(float x) {
  float a = fabsf(x);
  float e = __expf(-2.0f * a);
  float t = (1.0f - e) / (1.0f + e);
  return x < 0.0f ? -t : t;
}
__device__ __forceinline__ unsigned short f2bf(float f) {
  __hip_bfloat16 b = __float2bfloat16(f);
  return *reinterpret_cast<unsigned short*>(&b);
}
__device__ __forceinline__ float bf2f(unsigned short u) {
  return __uint_as_float(((unsigned int)u) << 16);
}

// ---- precompute: B-matrix [128 k][512 n] (n: Ui|Uo|Uu|Uf outputs) pre-shuffled into
// per-lane MFMA B-fragment layout: frag (T,K): lane L, elem j = B[k=32K+8*(L>>4)+j][n=16T+(L&15)]
// Flat: Wfrag[((T*4+K)*64+L)*8 + j] as bf16.
__global__ void k_wfrag(const float* __restrict__ Ui, const float* __restrict__ Uo,
                        const float* __restrict__ Uu, const float* __restrict__ Uf,
                        unsigned short* __restrict__ Wfrag) {
  int idx = blockIdx.x * 256 + threadIdx.x;  // 32*4*64 = 8192
  if (idx >= 8192) return;
  int L = idx & 63;
  int K = (idx >> 6) & 3;
  int T = idx >> 8;
  int n = 16 * T + (L & 15);
  int k0 = 32 * K + ((L >> 4) << 3);
  int g = n >> 7, o = n & 127;
  const float* U = (g == 0) ? Ui : (g == 1) ? Uo : (g == 2) ? Uu : Uf;
  unsigned short out[8];
  #pragma unroll
  for (int j = 0; j < 8; ++j) out[j] = f2bf(U[o * 128 + k0 + j]);
  *(int4*)(Wfrag + (size_t)idx * 8) = *(int4*)out;
}

// ---- precompute: leaf h (bf16) / c (fp32) tables, one block per vocab id ----
__global__ void k_leaf(const float* __restrict__ emb, const float* __restrict__ Wp, const float* __restrict__ bp,
                       const float* __restrict__ Wi, const float* __restrict__ bi,
                       const float* __restrict__ Wo, const float* __restrict__ bo,
                       const float* __restrict__ Wu, const float* __restrict__ bu,
                       unsigned short* __restrict__ leaf_h8, float* __restrict__ leaf_c) {
  int v = blockIdx.x, o = threadIdx.x;
  __shared__ float x[128];
  float acc = bp[o];
  if (v != 0) {  // reference zeroes emb row 0
    for (int e = 0; e < E_; ++e) acc = fmaf(emb[v * E_ + e], Wp[o * E_ + e], acc);
  }
  x[o] = acc;
  __syncthreads();
  float zi = bi[o], zo = bo[o], zu = bu[o];
  for (int k = 0; k < H_; ++k) {
    float xv = x[k];
    zi = fmaf(xv, Wi[o * H_ + k], zi);
    zo = fmaf(xv, Wo[o * H_ + k], zo);
    zu = fmaf(xv, Wu[o * H_ + k], zu);
  }
  float gi = sigm(zi), go = sigm(zo), gu = tanh_(zu);
  float c = gi * gu;
  leaf_c[v * H_ + o] = c;
  leaf_h8[v * H_ + o] = f2bf(go * tanh_(c));
}

// ---- precompute: per-symbol x-side gate pre-activations [S][4][128] (i,o,u,f), fp32 ----
__global__ void k_sym(const float* __restrict__ sym_emb, const float* __restrict__ Wp, const float* __restrict__ bp,
                      const float* __restrict__ Wi, const float* __restrict__ bi,
                      const float* __restrict__ Wo, const float* __restrict__ bo,
                      const float* __restrict__ Wu, const float* __restrict__ bu,
                      const float* __restrict__ Wf, const float* __restrict__ bf,
                      float* __restrict__ symx) {
  int s = blockIdx.x, o = threadIdx.x;
  __shared__ float x[128];
  float acc = bp[o];
  for (int e = 0; e < E_; ++e) acc = fmaf(sym_emb[s * E_ + e], Wp[o * E_ + e], acc);
  x[o] = acc;
  __syncthreads();
  float zi = bi[o], zo = bo[o], zu = bu[o], zf = bf[o];
  for (int k = 0; k < H_; ++k) {
    float xv = x[k];
    zi = fmaf(xv, Wi[o * H_ + k], zi);
    zo = fmaf(xv, Wo[o * H_ + k], zo);
    zu = fmaf(xv, Wu[o * H_ + k], zu);
    zf = fmaf(xv, Wf[o * H_ + k], zf);
  }
  size_t base = (size_t)s * 4 * H_;
  symx[base + 0 * H_ + o] = zi;
  symx[base + 1 * H_ + o] = zo;
  symx[base + 2 * H_ + o] = zu;
  symx[base + 3 * H_ + o] = zf;
}

// ---- one tree level via MFMA: 16 nodes/block (M=32 child rows), N=512, K=128 ----
// Wave w owns row-tiles {0,1} x col-tiles {w+4*ct, ct=0..7}; gate combine is in-register.
template <bool LEAF>
__global__ void __launch_bounds__(256, 2) k_level(
    const unsigned short* __restrict__ Wfrag, const float* __restrict__ symx,
    const int* __restrict__ symbols, int sym_off, int lgm,
    const unsigned short* __restrict__ h_prev8, const float* __restrict__ c_prev,
    const int* __restrict__ tokens,
    const unsigned short* __restrict__ leaf_h8, const float* __restrict__ leaf_c,
    unsigned short* __restrict__ h_out8, float* __restrict__ c_out) {
  __shared__ __align__(16) unsigned short Asm[32][136];  // 128 + 8 pad shorts (272B stride)
  int t = threadIdx.x;
  int g0 = blockIdx.x * 16;  // first node of block
  int w = t >> 6, L = t & 63, q = L >> 4, cL = L & 15;

  // stage A (32 child h rows x 128 bf16) into LDS, coalesced int4
  #pragma unroll
  for (int i = 0; i < 2; ++i) {
    int row = (t >> 4) + 16 * i;
    int co = (t & 15) * 8;  // short offset
    const unsigned short* src;
    if (LEAF) {
      src = leaf_h8 + (size_t)tokens[2 * g0 + row] * H_ + co;
    } else {
      src = h_prev8 + (size_t)(2 * g0 + row) * H_ + co;
    }
    *(int4*)&Asm[row][co] = *(const int4*)src;
  }
  __syncthreads();

  f32x4 acc[2][8];
  #pragma unroll
  for (int r = 0; r < 2; ++r)
    #pragma unroll
    for (int ct = 0; ct < 8; ++ct) acc[r][ct] = (f32x4){0.f, 0.f, 0.f, 0.f};

  const short8* wf = (const short8*)Wfrag;
  #pragma unroll
  for (int K = 0; K < 4; ++K) {
    short8 bfr[8];
    #pragma unroll
    for (int ct = 0; ct < 8; ++ct) {
      int T = w + 4 * ct;
      bfr[ct] = wf[(size_t)(T * 4 + K) * 64 + L];
    }
    short8 a0 = *(const short8*)&Asm[cL][K * 32 + q * 8];
    short8 a1 = *(const short8*)&Asm[16 + cL][K * 32 + q * 8];
    #pragma unroll
    for (int ct = 0; ct < 8; ++ct) {
      acc[0][ct] = __builtin_amdgcn_mfma_f32_16x16x32_bf16(a0, bfr[ct], acc[0][ct], 0, 0, 0);
      acc[1][ct] = __builtin_amdgcn_mfma_f32_16x16x32_bf16(a1, bfr[ct], acc[1][ct], 0, 0, 0);
    }
  }

  // epilogue: C/D layout col=lane&15, row=4q+reg. Node pair (left,right) = reg pairs (0,1),(2,3).
  int mmask = (1 << lgm) - 1;
  #pragma unroll
  for (int r = 0; r < 2; ++r) {
    #pragma unroll
    for (int nd = 0; nd < 2; ++nd) {
      int g = g0 + 8 * r + 2 * q + nd;
      int bb = g >> lgm, jj = g & mmask;
      int s = symbols[bb * (N_ - 1) + sym_off + jj];
      const float* sx = symx + (size_t)s * 512;
      const float* clp;
      const float* crp;
      if (LEAF) {
        clp = leaf_c + (size_t)tokens[2 * g] * H_;
        crp = leaf_c + (size_t)tokens[2 * g + 1] * H_;
      } else {
        clp = c_prev + (size_t)(2 * g) * H_;
        crp = c_prev + (size_t)(2 * g + 1) * H_;
      }
      #pragma unroll
      for (int k = 0; k < 2; ++k) {
        int c = 16 * (w + 4 * k) + cL;  // hidden unit index, 0..127
        float i_p = acc[r][k][2 * nd] + acc[r][k][2 * nd + 1];
        float o_p = acc[r][k + 2][2 * nd] + acc[r][k + 2][2 * nd + 1];
        float u_p = acc[r][k + 4][2 * nd] + acc[r][k + 4][2 * nd + 1];
        float fl_p = acc[r][k + 6][2 * nd];
        float fr_p = acc[r][k + 6][2 * nd + 1];
        float gi = sigm(sx[0 * H_ + c] + i_p);
        float go = sigm(sx[1 * H_ + c] + o_p);
        float gu = tanh_(sx[2 * H_ + c] + u_p);
        float fx = sx[3 * H_ + c];
        float fl = sigm(fx + fl_p);
        float fr = sigm(fx + fr_p);
        float cv = fmaf(gi, gu, fmaf(fl, clp[c], fr * crp[c]));
        c_out[(size_t)g * H_ + c] = cv;
        h_out8[(size_t)g * H_ + c] = f2bf(go * tanh_(cv));
      }
    }
  }
}

// ---- final projection: out = root_h @ Wout.T + bout ----
__global__ void k_out(const unsigned short* __restrict__ hroot8, const float* __restrict__ Wout,
                      const float* __restrict__ bout, float* __restrict__ out) {
  int b = blockIdx.x, o = threadIdx.x;
  __shared__ float hr[128];
  hr[o] = bf2f(hroot8[(size_t)b * H_ + o]);
  __syncthreads();
  float acc = bout[o];
  for (int k = 0; k < H_; ++k) acc = fmaf(hr[k], Wout[o * H_ + k], acc);
  out[(size_t)b * H_ + o] = acc;
}

extern "C" void kernel_launch(void* const* d_in, const int* in_sizes, int n_in,
                              void* d_out, int out_size, void* d_ws, size_t ws_size,
                              hipStream_t stream) {
  const int* tokens    = (const int*)d_in[0];
  const int* symbols   = (const int*)d_in[1];
  const float* emb     = (const float*)d_in[2];
  const float* sym_emb = (const float*)d_in[3];
  const float* Wp  = (const float*)d_in[4];
  const float* bp  = (const float*)d_in[5];
  const float* Wi  = (const float*)d_in[6];
  const float* bi  = (const float*)d_in[7];
  const float* Ui  = (const float*)d_in[8];
  const float* Wf  = (const float*)d_in[9];
  const float* bf  = (const float*)d_in[10];
  const float* Uf  = (const float*)d_in[11];
  const float* Wo  = (const float*)d_in[12];
  const float* bo  = (const float*)d_in[13];
  const float* Uo  = (const float*)d_in[14];
  const float* Wu  = (const float*)d_in[15];
  const float* bu  = (const float*)d_in[16];
  const float* Uu  = (const float*)d_in[17];
  const float* Wout= (const float*)d_in[18];
  const float* bout= (const float*)d_in[19];

  // Workspace layout (~151.3 MB total; fits known-good 201.7 MB budget)
  char* ws = (char*)d_ws;
  unsigned short* Wfrag   = (unsigned short*)(ws);                    // 131072 B
  unsigned short* leaf_h8 = (unsigned short*)(ws + 131072);           // 5376 B
  float*          leaf_c  = (float*)(ws + 136448);                    // 10752 B
  float*          symx    = (float*)(ws + 147200);                    // 102400 B
  unsigned short* A_h8    = (unsigned short*)(ws + 249600);           // 131072*128*2 = 33554432 B
  float*          A_c     = (float*)(ws + 249600 + 33554432UL);       // 67108864 B
  unsigned short* B_h8    = (unsigned short*)(ws + 249600 + 100663296UL); // 65536*128*2 = 16777216 B
  float*          B_c     = (float*)(ws + 249600 + 117440512UL);      // 33554432 B

  k_wfrag<<<32, 256, 0, stream>>>(Ui, Uo, Uu, Uf, Wfrag);
  k_leaf<<<V_, 128, 0, stream>>>(emb, Wp, bp, Wi, bi, Wo, bo, Wu, bu, leaf_h8, leaf_c);
  k_sym<<<S_, 128, 0, stream>>>(sym_emb, Wp, bp, Wi, bi, Wo, bo, Wu, bu, Wf, bf, symx);

  unsigned short* prev_h = nullptr;
  float* prev_c = nullptr;
  int off = 0;
  for (int l = 1; l <= 12; ++l) {
    int m = N_ >> l;
    int M = B_ * m;           // nodes this level
    int lgm = 12 - l;
    unsigned short* oh = (l & 1) ? A_h8 : B_h8;
    float* oc = (l & 1) ? A_c : B_c;
    if (l == 1) {
      k_level<true><<<M / 16, 256, 0, stream>>>(Wfrag, symx, symbols, off, lgm,
          nullptr, nullptr, tokens, leaf_h8, leaf_c, oh, oc);
    } else {
      k_level<false><<<M / 16, 256, 0, stream>>>(Wfrag, symx, symbols, off, lgm,
          prev_h, prev_c, nullptr, nullptr, nullptr, oh, oc);
    }
    prev_h = oh;
    prev_c = oc;
    off += m;
  }
  k_out<<<B_, 128, 0, stream>>>(prev_h, Wout, bout, (float*)d_out);
}

// Round 4
// 306.670 us; speedup vs baseline: 3.5121x; 1.1320x over previous
//
#include <hip/hip_runtime.h>
#include <hip/hip_bf16.h>

typedef __attribute__((ext_vector_type(8))) short short8;
typedef __attribute__((ext_vector_type(4))) float f32x4;

static constexpr int B_ = 64;
static constexpr int N_ = 4096;
static constexpr int V_ = 21;
static constexpr int S_ = 50;
static constexpr int E_ = 64;
static constexpr int H_ = 128;
static constexpr int NPAIR = V_ * V_;        // 441
static constexpr int NTAB = NPAIR * S_;      // 22050

__device__ __forceinline__ float sigm(float x) { return 1.0f / (1.0f + __expf(-x)); }
__device__ __forceinline__ float tanh_(float x) {
  float a = fabsf(x);
  float e = __expf(-2.0f * a);
  float t = (1.0f - e) / (1.0f + e);
  return x < 0.0f ? -t : t;
}
__device__ __forceinline__ unsigned short f2bf(float f) {
  __hip_bfloat16 b = __float2bfloat16(f);
  return *reinterpret_cast<unsigned short*>(&b);
}
__device__ __forceinline__ float bf2f(unsigned short u) {
  return __uint_as_float(((unsigned int)u) << 16);
}

// ---- fused precompute: Wfrag (blocks 0..31), leaf tables (32..52), symx (53..102) ----
// Wfrag layout: frag (T,K): lane L, elem j = B[k=32K+8*(L>>4)+j][n=16T+(L&15)], bf16.
__global__ void k_pre(const float* __restrict__ emb, const float* __restrict__ sym_emb,
                      const float* __restrict__ Wp, const float* __restrict__ bp,
                      const float* __restrict__ Wi, const float* __restrict__ bi, const float* __restrict__ Ui,
                      const float* __restrict__ Wf, const float* __restrict__ bf, const float* __restrict__ Uf,
                      const float* __restrict__ Wo, const float* __restrict__ bo, const float* __restrict__ Uo,
                      const float* __restrict__ Wu, const float* __restrict__ bu, const float* __restrict__ Uu,
                      unsigned short* __restrict__ Wfrag,
                      unsigned short* __restrict__ leaf_h8, float* __restrict__ leaf_c,
                      float* __restrict__ symx) {
  int blk = blockIdx.x, t = threadIdx.x;
  if (blk < 32) {
    int idx = blk * 256 + t;  // 8192 fragments*lane entries
    int L = idx & 63;
    int K = (idx >> 6) & 3;
    int T = idx >> 8;
    int n = 16 * T + (L & 15);
    int k0 = 32 * K + ((L >> 4) << 3);
    int g = n >> 7, o = n & 127;
    const float* U = (g == 0) ? Ui : (g == 1) ? Uo : (g == 2) ? Uu : Uf;
    unsigned short out[8];
    #pragma unroll
    for (int j = 0; j < 8; ++j) out[j] = f2bf(U[o * 128 + k0 + j]);
    *(int4*)(Wfrag + (size_t)idx * 8) = *(int4*)out;
  } else if (blk < 32 + V_) {
    int v = blk - 32;
    __shared__ float x[128];
    if (t < 128) {
      float acc = bp[t];
      if (v != 0) {  // reference zeroes emb row 0
        for (int e = 0; e < E_; ++e) acc = fmaf(emb[v * E_ + e], Wp[t * E_ + e], acc);
      }
      x[t] = acc;
    }
    __syncthreads();
    if (t < 128) {
      float zi = bi[t], zo = bo[t], zu = bu[t];
      for (int k = 0; k < H_; ++k) {
        float xv = x[k];
        zi = fmaf(xv, Wi[t * H_ + k], zi);
        zo = fmaf(xv, Wo[t * H_ + k], zo);
        zu = fmaf(xv, Wu[t * H_ + k], zu);
      }
      float gi = sigm(zi), go = sigm(zo), gu = tanh_(zu);
      float c = gi * gu;
      leaf_c[v * H_ + t] = c;
      leaf_h8[v * H_ + t] = f2bf(go * tanh_(c));
    }
  } else {
    int s = blk - 32 - V_;
    __shared__ float x[128];
    if (t < 128) {
      float acc = bp[t];
      for (int e = 0; e < E_; ++e) acc = fmaf(sym_emb[s * E_ + e], Wp[t * E_ + e], acc);
      x[t] = acc;
    }
    __syncthreads();
    if (t < 128) {
      float zi = bi[t], zo = bo[t], zu = bu[t], zf = bf[t];
      for (int k = 0; k < H_; ++k) {
        float xv = x[k];
        zi = fmaf(xv, Wi[t * H_ + k], zi);
        zo = fmaf(xv, Wo[t * H_ + k], zo);
        zu = fmaf(xv, Wu[t * H_ + k], zu);
        zf = fmaf(xv, Wf[t * H_ + k], zf);
      }
      size_t base = (size_t)s * 4 * H_;
      symx[base + 0 * H_ + t] = zi;
      symx[base + 1 * H_ + t] = zo;
      symx[base + 2 * H_ + t] = zu;
      symx[base + 3 * H_ + t] = zf;
    }
  }
}

// ---- level-1 virtualization: node table over (tl,tr,s) triples + per-node index ----
// blocks [0,441): tab rows p*50+s for pair p=(tl*21+tr). blocks [441,953): idx1.
__global__ void k_tabidx(const unsigned short* __restrict__ leaf_h8, const float* __restrict__ leaf_c,
                         const float* __restrict__ symx,
                         const float* __restrict__ Ui, const float* __restrict__ Uo,
                         const float* __restrict__ Uu, const float* __restrict__ Uf,
                         const int* __restrict__ tokens, const int* __restrict__ symbols,
                         unsigned short* __restrict__ tab_h8, float* __restrict__ tab_c,
                         int* __restrict__ idx1) {
  int p = blockIdx.x, t = threadIdx.x;
  if (p < NPAIR) {
    int tl = p / V_, tr = p % V_;
    __shared__ float hl[128], hr[128];
    if (t < 128) {
      hl[t] = bf2f(leaf_h8[tl * H_ + t]);
      hr[t] = bf2f(leaf_h8[tr * H_ + t]);
    }
    __syncthreads();
    if (t < 128) {
      float zi = 0.f, zo = 0.f, zu = 0.f, pfl = 0.f, pfr = 0.f;
      for (int k = 0; k < H_; ++k) {
        float l = hl[k], r = hr[k], ht = l + r;
        zi = fmaf(ht, Ui[t * H_ + k], zi);
        zo = fmaf(ht, Uo[t * H_ + k], zo);
        zu = fmaf(ht, Uu[t * H_ + k], zu);
        float wf = Uf[t * H_ + k];
        pfl = fmaf(l, wf, pfl);
        pfr = fmaf(r, wf, pfr);
      }
      float cl = leaf_c[tl * H_ + t], cr = leaf_c[tr * H_ + t];
      for (int s = 0; s < S_; ++s) {
        const float* sx = symx + (size_t)s * 512;
        float gi = sigm(sx[0 * H_ + t] + zi);
        float go = sigm(sx[1 * H_ + t] + zo);
        float gu = tanh_(sx[2 * H_ + t] + zu);
        float fx = sx[3 * H_ + t];
        float fl = sigm(fx + pfl);
        float fr = sigm(fx + pfr);
        float cv = fmaf(gi, gu, fmaf(fl, cl, fr * cr));
        size_t row = (size_t)(p * S_ + s);
        tab_c[row * H_ + t] = cv;
        tab_h8[row * H_ + t] = f2bf(go * tanh_(cv));
      }
    }
  } else {
    int g = (p - NPAIR) * 256 + t;  // 512*256 = 131072 level-1 nodes, flat (b*2048+j)
    int b = g >> 11, j = g & 2047;
    int tl = tokens[b * N_ + 2 * j];
    int tr = tokens[b * N_ + 2 * j + 1];
    int s = symbols[b * (N_ - 1) + j];
    idx1[g] = (tl * V_ + tr) * S_ + s;
  }
}

// ---- one tree level via MFMA: 16 nodes/block (M=32 child rows), N=512, K=128 ----
// GATHER: children come from the 22050-row triple table via gidx (level 2).
template <bool GATHER>
__global__ void __launch_bounds__(256, 2) k_level(
    const unsigned short* __restrict__ Wfrag, const float* __restrict__ symx,
    const int* __restrict__ symbols, int sym_off, int lgm,
    const unsigned short* __restrict__ h_prev8, const float* __restrict__ c_prev,
    const int* __restrict__ gidx,
    const unsigned short* __restrict__ gh8, const float* __restrict__ gc,
    unsigned short* __restrict__ h_out8, float* __restrict__ c_out) {
  __shared__ __align__(16) unsigned short Asm[32][136];  // 128 + 8 pad shorts
  int t = threadIdx.x;
  int g0 = blockIdx.x * 16;
  int w = t >> 6, L = t & 63, q = L >> 4, cL = L & 15;

  // stage A (32 child h rows x 128 bf16) into LDS, coalesced int4
  #pragma unroll
  for (int i = 0; i < 2; ++i) {
    int row = (t >> 4) + 16 * i;
    int co = (t & 15) * 8;
    const unsigned short* src;
    if (GATHER) {
      src = gh8 + (size_t)gidx[2 * g0 + row] * H_ + co;
    } else {
      src = h_prev8 + (size_t)(2 * g0 + row) * H_ + co;
    }
    *(int4*)&Asm[row][co] = *(const int4*)src;
  }
  __syncthreads();

  f32x4 acc[2][8];
  #pragma unroll
  for (int r = 0; r < 2; ++r)
    #pragma unroll
    for (int ct = 0; ct < 8; ++ct) acc[r][ct] = (f32x4){0.f, 0.f, 0.f, 0.f};

  const short8* wf = (const short8*)Wfrag;
  #pragma unroll
  for (int K = 0; K < 4; ++K) {
    short8 bfr[8];
    #pragma unroll
    for (int ct = 0; ct < 8; ++ct) {
      int T = w + 4 * ct;
      bfr[ct] = wf[(size_t)(T * 4 + K) * 64 + L];
    }
    short8 a0 = *(const short8*)&Asm[cL][K * 32 + q * 8];
    short8 a1 = *(const short8*)&Asm[16 + cL][K * 32 + q * 8];
    #pragma unroll
    for (int ct = 0; ct < 8; ++ct) {
      acc[0][ct] = __builtin_amdgcn_mfma_f32_16x16x32_bf16(a0, bfr[ct], acc[0][ct], 0, 0, 0);
      acc[1][ct] = __builtin_amdgcn_mfma_f32_16x16x32_bf16(a1, bfr[ct], acc[1][ct], 0, 0, 0);
    }
  }

  // epilogue: C/D layout col=lane&15, row=4q+reg. Node pair (left,right) = reg pairs.
  int mmask = (1 << lgm) - 1;
  #pragma unroll
  for (int r = 0; r < 2; ++r) {
    #pragma unroll
    for (int nd = 0; nd < 2; ++nd) {
      int g = g0 + 8 * r + 2 * q + nd;
      int bb = g >> lgm, jj = g & mmask;
      int s = symbols[bb * (N_ - 1) + sym_off + jj];
      const float* sx = symx + (size_t)s * 512;
      const float* clp;
      const float* crp;
      if (GATHER) {
        clp = gc + (size_t)gidx[2 * g] * H_;
        crp = gc + (size_t)gidx[2 * g + 1] * H_;
      } else {
        clp = c_prev + (size_t)(2 * g) * H_;
        crp = c_prev + (size_t)(2 * g + 1) * H_;
      }
      #pragma unroll
      for (int k = 0; k < 2; ++k) {
        int c = 16 * (w + 4 * k) + cL;
        float i_p = acc[r][k][2 * nd] + acc[r][k][2 * nd + 1];
        float o_p = acc[r][k + 2][2 * nd] + acc[r][k + 2][2 * nd + 1];
        float u_p = acc[r][k + 4][2 * nd] + acc[r][k + 4][2 * nd + 1];
        float fl_p = acc[r][k + 6][2 * nd];
        float fr_p = acc[r][k + 6][2 * nd + 1];
        float gi = sigm(sx[0 * H_ + c] + i_p);
        float go = sigm(sx[1 * H_ + c] + o_p);
        float gu = tanh_(sx[2 * H_ + c] + u_p);
        float fx = sx[3 * H_ + c];
        float fl = sigm(fx + fl_p);
        float fr = sigm(fx + fr_p);
        float cv = fmaf(gi, gu, fmaf(fl, clp[c], fr * crp[c]));
        c_out[(size_t)g * H_ + c] = cv;
        h_out8[(size_t)g * H_ + c] = f2bf(go * tanh_(cv));
      }
    }
  }
}

// ---- final projection: out = root_h @ Wout.T + bout ----
__global__ void k_out(const unsigned short* __restrict__ hroot8, const float* __restrict__ Wout,
                      const float* __restrict__ bout, float* __restrict__ out) {
  int b = blockIdx.x, o = threadIdx.x;
  __shared__ float hr[128];
  hr[o] = bf2f(hroot8[(size_t)b * H_ + o]);
  __syncthreads();
  float acc = bout[o];
  for (int k = 0; k < H_; ++k) acc = fmaf(hr[k], Wout[o * H_ + k], acc);
  out[(size_t)b * H_ + o] = acc;
}

extern "C" void kernel_launch(void* const* d_in, const int* in_sizes, int n_in,
                              void* d_out, int out_size, void* d_ws, size_t ws_size,
                              hipStream_t stream) {
  const int* tokens    = (const int*)d_in[0];
  const int* symbols   = (const int*)d_in[1];
  const float* emb     = (const float*)d_in[2];
  const float* sym_emb = (const float*)d_in[3];
  const float* Wp  = (const float*)d_in[4];
  const float* bp  = (const float*)d_in[5];
  const float* Wi  = (const float*)d_in[6];
  const float* bi  = (const float*)d_in[7];
  const float* Ui  = (const float*)d_in[8];
  const float* Wf  = (const float*)d_in[9];
  const float* bf  = (const float*)d_in[10];
  const float* Uf  = (const float*)d_in[11];
  const float* Wo  = (const float*)d_in[12];
  const float* bo  = (const float*)d_in[13];
  const float* Uo  = (const float*)d_in[14];
  const float* Wu  = (const float*)d_in[15];
  const float* bu  = (const float*)d_in[16];
  const float* Uu  = (const float*)d_in[17];
  const float* Wout= (const float*)d_in[18];
  const float* bout= (const float*)d_in[19];

  // Workspace layout (~93.2 MB total; well under the 151 MB known-good budget)
  char* ws = (char*)d_ws;
  unsigned short* Wfrag   = (unsigned short*)(ws);                  // 131072 B
  unsigned short* leaf_h8 = (unsigned short*)(ws + 131072);         // 5376 B
  float*          leaf_c  = (float*)(ws + 136448);                  // 10752 B
  float*          symx    = (float*)(ws + 147200);                  // 102400 B
  unsigned short* tab_h8  = (unsigned short*)(ws + 249600);         // 22050*128*2 = 5644800 B
  float*          tab_c   = (float*)(ws + 5894400UL);               // 22050*128*4 = 11289600 B
  int*            idx1    = (int*)(ws + 17184000UL);                // 131072*4 = 524288 B
  unsigned short* A_h8    = (unsigned short*)(ws + 17708288UL);     // 65536*128*2 = 16777216 B
  float*          A_c     = (float*)(ws + 34485504UL);              // 65536*128*4 = 33554432 B
  unsigned short* B_h8    = (unsigned short*)(ws + 68039936UL);     // 32768*128*2 = 8388608 B
  float*          B_c     = (float*)(ws + 76428544UL);              // 32768*128*4 = 16777216 B

  k_pre<<<32 + V_ + S_, 256, 0, stream>>>(emb, sym_emb, Wp, bp,
      Wi, bi, Ui, Wf, bf, Uf, Wo, bo, Uo, Wu, bu, Uu,
      Wfrag, leaf_h8, leaf_c, symx);
  k_tabidx<<<NPAIR + 512, 256, 0, stream>>>(leaf_h8, leaf_c, symx,
      Ui, Uo, Uu, Uf, tokens, symbols, tab_h8, tab_c, idx1);

  unsigned short* prev_h = nullptr;
  float* prev_c = nullptr;
  int off = 2048;  // symbols consumed by level 1
  for (int l = 2; l <= 12; ++l) {
    int m = N_ >> l;
    int M = B_ * m;
    int lgm = 12 - l;
    unsigned short* oh = (l & 1) ? B_h8 : A_h8;
    float* oc = (l & 1) ? B_c : A_c;
    if (l == 2) {
      k_level<true><<<M / 16, 256, 0, stream>>>(Wfrag, symx, symbols, off, lgm,
          nullptr, nullptr, idx1, tab_h8, tab_c, oh, oc);
    } else {
      k_level<false><<<M / 16, 256, 0, stream>>>(Wfrag, symx, symbols, off, lgm,
          prev_h, prev_c, nullptr, nullptr, nullptr, oh, oc);
    }
    prev_h = oh;
    prev_c = oc;
    off += m;
  }
  k_out<<<B_, 128, 0, stream>>>(prev_h, Wout, bout, (float*)d_out);
}

// Round 5
// 266.611 us; speedup vs baseline: 4.0398x; 1.1503x over previous
//
#include <hip/hip_runtime.h>
#include <hip/hip_bf16.h>

typedef __attribute__((ext_vector_type(8))) short short8;
typedef __attribute__((ext_vector_type(4))) float f32x4;

static constexpr int B_ = 64;
static constexpr int N_ = 4096;
static constexpr int V_ = 21;
static constexpr int S_ = 50;
static constexpr int E_ = 64;
static constexpr int H_ = 128;
static constexpr int NPAIR = V_ * V_;   // 441
static constexpr int NTAB = NPAIR * S_; // 22050

__device__ __forceinline__ float sigm(float x) { return 1.0f / (1.0f + __expf(-x)); }
__device__ __forceinline__ float tanh_(float x) {
  float a = fabsf(x);
  float e = __expf(-2.0f * a);
  float t = (1.0f - e) / (1.0f + e);
  return x < 0.0f ? -t : t;
}
__device__ __forceinline__ unsigned short f2bf(float f) {
  __hip_bfloat16 b = __float2bfloat16(f);
  return *reinterpret_cast<unsigned short*>(&b);
}
__device__ __forceinline__ float bf2f(unsigned short u) {
  return __uint_as_float(((unsigned int)u) << 16);
}

// ---- fused precompute ----
// blocks 0..31: Wfrag (bf16 MFMA B-fragments); 32..52: leaf tables; 53..102: symx;
// 103..134: Wt fp32 k-major [128][512] for coalesced table matvec.
__global__ void k_pre(const float* __restrict__ emb, const float* __restrict__ sym_emb,
                      const float* __restrict__ Wp, const float* __restrict__ bp,
                      const float* __restrict__ Wi, const float* __restrict__ bi, const float* __restrict__ Ui,
                      const float* __restrict__ Wf, const float* __restrict__ bf, const float* __restrict__ Uf,
                      const float* __restrict__ Wo, const float* __restrict__ bo, const float* __restrict__ Uo,
                      const float* __restrict__ Wu, const float* __restrict__ bu, const float* __restrict__ Uu,
                      unsigned short* __restrict__ Wfrag, float* __restrict__ Wt,
                      unsigned short* __restrict__ leaf_h8, float* __restrict__ leaf_c,
                      float* __restrict__ symx) {
  int blk = blockIdx.x, t = threadIdx.x;
  if (blk < 32) {
    int idx = blk * 256 + t;  // 8192 frag*lane entries
    int L = idx & 63;
    int K = (idx >> 6) & 3;
    int T = idx >> 8;
    int n = 16 * T + (L & 15);
    int k0 = 32 * K + ((L >> 4) << 3);
    int g = n >> 7, o = n & 127;
    const float* U = (g == 0) ? Ui : (g == 1) ? Uo : (g == 2) ? Uu : Uf;
    unsigned short out[8];
    #pragma unroll
    for (int j = 0; j < 8; ++j) out[j] = f2bf(U[o * 128 + k0 + j]);
    *(int4*)(Wfrag + (size_t)idx * 8) = *(int4*)out;
  } else if (blk < 32 + V_) {
    int v = blk - 32;
    __shared__ float x[128];
    if (t < 128) {
      float acc = bp[t];
      if (v != 0) {  // reference zeroes emb row 0
        for (int e = 0; e < E_; ++e) acc = fmaf(emb[v * E_ + e], Wp[t * E_ + e], acc);
      }
      x[t] = acc;
    }
    __syncthreads();
    if (t < 128) {
      float zi = bi[t], zo = bo[t], zu = bu[t];
      for (int k = 0; k < H_; ++k) {
        float xv = x[k];
        zi = fmaf(xv, Wi[t * H_ + k], zi);
        zo = fmaf(xv, Wo[t * H_ + k], zo);
        zu = fmaf(xv, Wu[t * H_ + k], zu);
      }
      float gi = sigm(zi), go = sigm(zo), gu = tanh_(zu);
      float c = gi * gu;
      leaf_c[v * H_ + t] = c;
      leaf_h8[v * H_ + t] = f2bf(go * tanh_(c));
    }
  } else if (blk < 32 + V_ + S_) {
    int s = blk - 32 - V_;
    __shared__ float x[128];
    if (t < 128) {
      float acc = bp[t];
      for (int e = 0; e < E_; ++e) acc = fmaf(sym_emb[s * E_ + e], Wp[t * E_ + e], acc);
      x[t] = acc;
    }
    __syncthreads();
    if (t < 128) {
      float zi = bi[t], zo = bo[t], zu = bu[t], zf = bf[t];
      for (int k = 0; k < H_; ++k) {
        float xv = x[k];
        zi = fmaf(xv, Wi[t * H_ + k], zi);
        zo = fmaf(xv, Wo[t * H_ + k], zo);
        zu = fmaf(xv, Wu[t * H_ + k], zu);
        zf = fmaf(xv, Wf[t * H_ + k], zf);
      }
      size_t base = (size_t)s * 4 * H_;
      symx[base + 0 * H_ + t] = zi;
      symx[base + 1 * H_ + t] = zo;
      symx[base + 2 * H_ + t] = zu;
      symx[base + 3 * H_ + t] = zf;
    }
  } else {
    // Wt fp32 k-major: Wt[k*512 + gate*128 + o] = U_gate[o][k]
    int base = ((blk - 103) * 256 + t) * 8;  // 0..65528
    int k = base >> 9;
    int col = base & 511;
    int gg = col >> 7, o0 = col & 127;
    const float* U = (gg == 0) ? Ui : (gg == 1) ? Uo : (gg == 2) ? Uu : Uf;
    float v[8];
    #pragma unroll
    for (int j = 0; j < 8; ++j) v[j] = U[(o0 + j) * 128 + k];
    *(float4*)(Wt + base) = *(float4*)v;
    *(float4*)(Wt + base + 4) = *(float4*)(v + 4);
  }
}

// ---- table phase A: per-pair matvec pre-activations (coalesced via Wt) ----
// za[p][5][128] = {zi, zo, zu, pfl, pfr}
__global__ void k_tabA(const unsigned short* __restrict__ leaf_h8, const float* __restrict__ Wt,
                       float* __restrict__ za) {
  int p = blockIdx.x, t = threadIdx.x;  // 441 blocks x 128 threads
  int tl = p / V_, tr = p % V_;
  __shared__ float hl[128], hr[128];
  hl[t] = bf2f(leaf_h8[tl * H_ + t]);
  hr[t] = bf2f(leaf_h8[tr * H_ + t]);
  __syncthreads();
  float zi = 0.f, zo = 0.f, zu = 0.f, pfl = 0.f, pfr = 0.f;
  for (int k = 0; k < H_; ++k) {
    float l = hl[k], r = hr[k], ht = l + r;
    const float* wr = Wt + k * 512;
    zi = fmaf(ht, wr[t], zi);
    zo = fmaf(ht, wr[128 + t], zo);
    zu = fmaf(ht, wr[256 + t], zu);
    float wf = wr[384 + t];
    pfl = fmaf(l, wf, pfl);
    pfr = fmaf(r, wf, pfr);
  }
  float* z = za + (size_t)p * 640;
  z[t] = zi; z[128 + t] = zo; z[256 + t] = zu; z[384 + t] = pfl; z[512 + t] = pfr;
}

// ---- table phase B: elementwise gate epilogue over 22050 rows + idx1 build ----
__global__ void k_tabB(const float* __restrict__ za, const float* __restrict__ symx,
                       const float* __restrict__ leaf_c,
                       const int* __restrict__ tokens, const int* __restrict__ symbols,
                       unsigned short* __restrict__ tab_h8, float* __restrict__ tab_c,
                       int* __restrict__ idx1) {
  int blk = blockIdx.x, t = threadIdx.x;
  if (blk < NTAB / 2) {
    int row = blk * 2 + (t >> 7);
    int u = t & 127;
    int p = row / S_, s = row - p * S_;
    int tl = p / V_, tr = p - tl * V_;
    const float* z = za + (size_t)p * 640;
    const float* sx = symx + (size_t)s * 512;
    float gi = sigm(sx[u] + z[u]);
    float go = sigm(sx[128 + u] + z[128 + u]);
    float gu = tanh_(sx[256 + u] + z[256 + u]);
    float fx = sx[384 + u];
    float fl = sigm(fx + z[384 + u]);
    float fr = sigm(fx + z[512 + u]);
    float cv = fmaf(gi, gu, fmaf(fl, leaf_c[tl * H_ + u], fr * leaf_c[tr * H_ + u]));
    tab_c[(size_t)row * H_ + u] = cv;
    tab_h8[(size_t)row * H_ + u] = f2bf(go * tanh_(cv));
  } else {
    int g = (blk - NTAB / 2) * 256 + t;  // 131072 level-1 nodes
    int b = g >> 11, j = g & 2047;
    idx1[g] = (tokens[b * N_ + 2 * j] * V_ + tokens[b * N_ + 2 * j + 1]) * S_ + symbols[b * (N_ - 1) + j];
  }
}

// ---- fused subtree kernel: NLEV levels in-block, weights register-resident ----
// GATHER (levels 2-6): block = 16 level-2 nodes (subtree -> 1 level-6 node), A from table.
// !GATHER (levels 7-12): block = one batch row, A/c staged from level-6 buffers.
template <int L0, int NLEV, int AROWS, int C0R, int C1R, bool GATHER>
__global__ void __launch_bounds__(256, 2) k_tree(
    const unsigned short* __restrict__ Wfrag, const float* __restrict__ symx,
    const int* __restrict__ symbols,
    const int* __restrict__ idx1,
    const unsigned short* __restrict__ gh8, const float* __restrict__ gc,
    const unsigned short* __restrict__ in_h8, const float* __restrict__ in_c,
    unsigned short* __restrict__ out_h8, float* __restrict__ out_c,
    float* __restrict__ out_root) {
  __shared__ __align__(16) unsigned short Asm[AROWS][136];
  __shared__ float Csm0[C0R][128];
  __shared__ float Csm1[C1R][128];
  float* csm0 = &Csm0[0][0];
  float* csm1 = &Csm1[0][0];
  int t = threadIdx.x;
  int w = t >> 6, L = t & 63, q = L >> 4, cL = L & 15;
  int blk = blockIdx.x;
  int b, j0;
  if (GATHER) { b = blk >> 6; j0 = (blk & 63) << 4; }
  else { b = blk; j0 = 0; }

  // weight fragments -> registers, reused across all levels (32 x short8 = 128 VGPR)
  short8 wreg[8][4];
  const short8* wf = (const short8*)Wfrag;
  #pragma unroll
  for (int ct = 0; ct < 8; ++ct) {
    int T = w + 4 * ct;
    #pragma unroll
    for (int K = 0; K < 4; ++K) wreg[ct][K] = wf[(size_t)(T * 4 + K) * 64 + L];
  }

  // stage first-level children
  if (GATHER) {
    #pragma unroll
    for (int i = 0; i < 2; ++i) {
      int row = (t >> 4) + 16 * i;  // 0..31
      int co = (t & 15) * 8;
      *(int4*)&Asm[row][co] = *(const int4*)(gh8 + (size_t)idx1[(size_t)blk * 32 + row] * H_ + co);
    }
  } else {
    #pragma unroll
    for (int i = 0; i < 4; ++i) {
      int row = (t >> 4) + 16 * i;  // 0..63
      int co = (t & 15) * 8;
      *(int4*)&Asm[row][co] = *(const int4*)(in_h8 + (size_t)(b * 64 + row) * H_ + co);
    }
    #pragma unroll
    for (int i = 0; i < 8; ++i) {
      int fid = t + 256 * i;  // 64 rows x 32 float4
      int row = fid >> 5, c4 = (fid & 31) << 2;
      *(float4*)&Csm0[row][c4] = *(const float4*)(in_c + (size_t)(b * 64 + row) * H_ + c4);
    }
  }
  __syncthreads();

  int R = AROWS;
  #pragma unroll
  for (int lev = 0; lev < NLEV; ++lev) {
    const int l = L0 + lev;
    const int nodes = R >> 1;
    const int off = N_ - (N_ >> (l - 1));
    const int jb = b * (N_ - 1) + off + (j0 >> lev);
    const int nchunk = (R + 31) >> 5;
    for (int c = 0; c < nchunk; ++c) {
      f32x4 acc[2][8];
      #pragma unroll
      for (int r = 0; r < 2; ++r)
        #pragma unroll
        for (int ct = 0; ct < 8; ++ct) acc[r][ct] = (f32x4){0.f, 0.f, 0.f, 0.f};
      #pragma unroll
      for (int K = 0; K < 4; ++K) {
        short8 a0 = *(const short8*)&Asm[32 * c + cL][K * 32 + q * 8];
        short8 a1 = *(const short8*)&Asm[32 * c + 16 + cL][K * 32 + q * 8];
        #pragma unroll
        for (int ct = 0; ct < 8; ++ct) {
          acc[0][ct] = __builtin_amdgcn_mfma_f32_16x16x32_bf16(a0, wreg[ct][K], acc[0][ct], 0, 0, 0);
          acc[1][ct] = __builtin_amdgcn_mfma_f32_16x16x32_bf16(a1, wreg[ct][K], acc[1][ct], 0, 0, 0);
        }
      }
      __syncthreads();  // all GEMM reads of this chunk complete before epilogue writes Asm
      #pragma unroll
      for (int r = 0; r < 2; ++r) {
        #pragma unroll
        for (int nd = 0; nd < 2; ++nd) {
          int n = 16 * c + 8 * r + 2 * q + nd;  // node local id this level
          if (n < nodes) {
            int s = symbols[jb + n];
            const float* sx = symx + (size_t)s * 512;
            const float* clp;
            const float* crp;
            if (GATHER && lev == 0) {
              clp = gc + (size_t)idx1[(size_t)blk * 32 + 2 * n] * H_;
              crp = gc + (size_t)idx1[(size_t)blk * 32 + 2 * n + 1] * H_;
            } else {
              const float* crd = (l & 1) ? csm0 : csm1;  // read parity (l-1)&1
              clp = crd + (size_t)(2 * n) * 128;
              crp = crd + (size_t)(2 * n + 1) * 128;
            }
            float* cwr = (l & 1) ? csm1 : csm0;
            #pragma unroll
            for (int k = 0; k < 2; ++k) {
              int cc = 16 * (w + 4 * k) + cL;
              float i_p = acc[r][k][2 * nd] + acc[r][k][2 * nd + 1];
              float o_p = acc[r][k + 2][2 * nd] + acc[r][k + 2][2 * nd + 1];
              float u_p = acc[r][k + 4][2 * nd] + acc[r][k + 4][2 * nd + 1];
              float fl_p = acc[r][k + 6][2 * nd];
              float fr_p = acc[r][k + 6][2 * nd + 1];
              float gi = sigm(sx[cc] + i_p);
              float go = sigm(sx[128 + cc] + o_p);
              float gu = tanh_(sx[256 + cc] + u_p);
              float fx = sx[384 + cc];
              float fl = sigm(fx + fl_p);
              float fr = sigm(fx + fr_p);
              float cv = fmaf(gi, gu, fmaf(fl, clp[cc], fr * crp[cc]));
              float hv = go * tanh_(cv);
              if (lev == NLEV - 1) {
                if (GATHER) {
                  out_c[(size_t)blk * H_ + cc] = cv;
                  out_h8[(size_t)blk * H_ + cc] = f2bf(hv);
                } else {
                  out_root[(size_t)b * H_ + cc] = hv;
                }
              } else {
                cwr[(size_t)n * 128 + cc] = cv;
                Asm[n][cc] = f2bf(hv);
              }
            }
          }
        }
      }
      __syncthreads();  // epilogue writes visible before next GEMM
    }
    R >>= 1;
  }
}

// ---- final projection: out = root_h @ Wout.T + bout ----
__global__ void k_out(const float* __restrict__ hroot, const float* __restrict__ Wout,
                      const float* __restrict__ bout, float* __restrict__ out) {
  int b = blockIdx.x, o = threadIdx.x;
  __shared__ float hr[128];
  hr[o] = hroot[(size_t)b * H_ + o];
  __syncthreads();
  float acc = bout[o];
  for (int k = 0; k < H_; ++k) acc = fmaf(hr[k], Wout[o * H_ + k], acc);
  out[(size_t)b * H_ + o] = acc;
}

extern "C" void kernel_launch(void* const* d_in, const int* in_sizes, int n_in,
                              void* d_out, int out_size, void* d_ws, size_t ws_size,
                              hipStream_t stream) {
  const int* tokens    = (const int*)d_in[0];
  const int* symbols   = (const int*)d_in[1];
  const float* emb     = (const float*)d_in[2];
  const float* sym_emb = (const float*)d_in[3];
  const float* Wp  = (const float*)d_in[4];
  const float* bp  = (const float*)d_in[5];
  const float* Wi  = (const float*)d_in[6];
  const float* bi  = (const float*)d_in[7];
  const float* Ui  = (const float*)d_in[8];
  const float* Wf  = (const float*)d_in[9];
  const float* bf  = (const float*)d_in[10];
  const float* Uf  = (const float*)d_in[11];
  const float* Wo  = (const float*)d_in[12];
  const float* bo  = (const float*)d_in[13];
  const float* Uo  = (const float*)d_in[14];
  const float* Wu  = (const float*)d_in[15];
  const float* bu  = (const float*)d_in[16];
  const float* Uu  = (const float*)d_in[17];
  const float* Wout= (const float*)d_in[18];
  const float* bout= (const float*)d_in[19];

  // Workspace layout (~22.3 MB)
  char* ws = (char*)d_ws;
  unsigned short* Wfrag   = (unsigned short*)(ws);                // 131072
  float*          Wt      = (float*)(ws + 131072);                // 262144
  unsigned short* leaf_h8 = (unsigned short*)(ws + 393216);       // 5376
  float*          leaf_c  = (float*)(ws + 398592);                // 10752
  float*          symx    = (float*)(ws + 409344);                // 102400
  float*          za      = (float*)(ws + 511744);                // 441*640*4 = 1128960
  unsigned short* tab_h8  = (unsigned short*)(ws + 1640704);      // 22050*128*2 = 5644800
  float*          tab_c   = (float*)(ws + 7285504UL);             // 22050*128*4 = 11289600
  int*            idx1    = (int*)(ws + 18575104UL);              // 131072*4 = 524288
  unsigned short* l6_h8   = (unsigned short*)(ws + 19099392UL);   // 4096*128*2 = 1048576
  float*          l6_c    = (float*)(ws + 20147968UL);            // 4096*128*4 = 2097152
  float*          hroot   = (float*)(ws + 22245120UL);            // 64*128*4 = 32768

  k_pre<<<135, 256, 0, stream>>>(emb, sym_emb, Wp, bp,
      Wi, bi, Ui, Wf, bf, Uf, Wo, bo, Uo, Wu, bu, Uu,
      Wfrag, Wt, leaf_h8, leaf_c, symx);
  k_tabA<<<NPAIR, 128, 0, stream>>>(leaf_h8, Wt, za);
  k_tabB<<<NTAB / 2 + 512, 256, 0, stream>>>(za, symx, leaf_c, tokens, symbols,
      tab_h8, tab_c, idx1);
  // levels 2-6: 4096 blocks (16 level-2 nodes each -> 1 level-6 node)
  k_tree<2, 5, 32, 16, 8, true><<<4096, 256, 0, stream>>>(Wfrag, symx, symbols,
      idx1, tab_h8, tab_c, nullptr, nullptr, l6_h8, l6_c, nullptr);
  // levels 7-12: 64 blocks (one batch row each)
  k_tree<7, 6, 64, 64, 32, false><<<B_, 256, 0, stream>>>(Wfrag, symx, symbols,
      nullptr, nullptr, nullptr, l6_h8, l6_c, nullptr, nullptr, hroot);
  k_out<<<B_, 128, 0, stream>>>(hroot, Wout, bout, (float*)d_out);
}

// Round 6
// 231.548 us; speedup vs baseline: 4.6516x; 1.1514x over previous
//
#include <hip/hip_runtime.h>
#include <hip/hip_bf16.h>

typedef __attribute__((ext_vector_type(8))) short short8;
typedef __attribute__((ext_vector_type(4))) float f32x4;

static constexpr int B_ = 64;
static constexpr int N_ = 4096;
static constexpr int V_ = 21;
static constexpr int S_ = 50;
static constexpr int E_ = 64;
static constexpr int H_ = 128;
static constexpr int NPAIR = V_ * V_;   // 441
static constexpr int NTAB = NPAIR * S_; // 22050

__device__ __forceinline__ float rcp_(float x) { return __builtin_amdgcn_rcpf(x); }
__device__ __forceinline__ float sigm(float x) { return rcp_(1.0f + __expf(-x)); }
__device__ __forceinline__ float tanh_(float x) {
  float a = fabsf(x);
  float e = __expf(-2.0f * a);
  float t = (1.0f - e) * rcp_(1.0f + e);
  return x < 0.0f ? -t : t;
}
__device__ __forceinline__ unsigned short f2bf(float f) {
  __hip_bfloat16 b = __float2bfloat16(f);
  return *reinterpret_cast<unsigned short*>(&b);
}
__device__ __forceinline__ float bf2f(unsigned short u) {
  return __uint_as_float(((unsigned int)u) << 16);
}

// ---- fused precompute ----
// blocks 0..31: Wfrag (bf16 MFMA B-fragments); 32..52: leaf tables; 53..102: symx;
// 103..134: Wt fp32 k-major [128][512] for coalesced table matvec.
__global__ void k_pre(const float* __restrict__ emb, const float* __restrict__ sym_emb,
                      const float* __restrict__ Wp, const float* __restrict__ bp,
                      const float* __restrict__ Wi, const float* __restrict__ bi, const float* __restrict__ Ui,
                      const float* __restrict__ Wf, const float* __restrict__ bf, const float* __restrict__ Uf,
                      const float* __restrict__ Wo, const float* __restrict__ bo, const float* __restrict__ Uo,
                      const float* __restrict__ Wu, const float* __restrict__ bu, const float* __restrict__ Uu,
                      unsigned short* __restrict__ Wfrag, float* __restrict__ Wt,
                      unsigned short* __restrict__ leaf_h8, float* __restrict__ leaf_c,
                      float* __restrict__ symx) {
  int blk = blockIdx.x, t = threadIdx.x;
  if (blk < 32) {
    int idx = blk * 256 + t;
    int L = idx & 63;
    int K = (idx >> 6) & 3;
    int T = idx >> 8;
    int n = 16 * T + (L & 15);
    int k0 = 32 * K + ((L >> 4) << 3);
    int g = n >> 7, o = n & 127;
    const float* U = (g == 0) ? Ui : (g == 1) ? Uo : (g == 2) ? Uu : Uf;
    unsigned short out[8];
    #pragma unroll
    for (int j = 0; j < 8; ++j) out[j] = f2bf(U[o * 128 + k0 + j]);
    *(int4*)(Wfrag + (size_t)idx * 8) = *(int4*)out;
  } else if (blk < 32 + V_) {
    int v = blk - 32;
    __shared__ float x[128];
    if (t < 128) {
      float acc = bp[t];
      if (v != 0) {  // reference zeroes emb row 0
        for (int e = 0; e < E_; ++e) acc = fmaf(emb[v * E_ + e], Wp[t * E_ + e], acc);
      }
      x[t] = acc;
    }
    __syncthreads();
    if (t < 128) {
      float zi = bi[t], zo = bo[t], zu = bu[t];
      for (int k = 0; k < H_; ++k) {
        float xv = x[k];
        zi = fmaf(xv, Wi[t * H_ + k], zi);
        zo = fmaf(xv, Wo[t * H_ + k], zo);
        zu = fmaf(xv, Wu[t * H_ + k], zu);
      }
      float gi = sigm(zi), go = sigm(zo), gu = tanh_(zu);
      float c = gi * gu;
      leaf_c[v * H_ + t] = c;
      leaf_h8[v * H_ + t] = f2bf(go * tanh_(c));
    }
  } else if (blk < 32 + V_ + S_) {
    int s = blk - 32 - V_;
    __shared__ float x[128];
    if (t < 128) {
      float acc = bp[t];
      for (int e = 0; e < E_; ++e) acc = fmaf(sym_emb[s * E_ + e], Wp[t * E_ + e], acc);
      x[t] = acc;
    }
    __syncthreads();
    if (t < 128) {
      float zi = bi[t], zo = bo[t], zu = bu[t], zf = bf[t];
      for (int k = 0; k < H_; ++k) {
        float xv = x[k];
        zi = fmaf(xv, Wi[t * H_ + k], zi);
        zo = fmaf(xv, Wo[t * H_ + k], zo);
        zu = fmaf(xv, Wu[t * H_ + k], zu);
        zf = fmaf(xv, Wf[t * H_ + k], zf);
      }
      size_t base = (size_t)s * 4 * H_;
      symx[base + 0 * H_ + t] = zi;
      symx[base + 1 * H_ + t] = zo;
      symx[base + 2 * H_ + t] = zu;
      symx[base + 3 * H_ + t] = zf;
    }
  } else {
    int base = ((blk - 103) * 256 + t) * 8;
    int k = base >> 9;
    int col = base & 511;
    int gg = col >> 7, o0 = col & 127;
    const float* U = (gg == 0) ? Ui : (gg == 1) ? Uo : (gg == 2) ? Uu : Uf;
    float v[8];
    #pragma unroll
    for (int j = 0; j < 8; ++j) v[j] = U[(o0 + j) * 128 + k];
    *(float4*)(Wt + base) = *(float4*)v;
    *(float4*)(Wt + base + 4) = *(float4*)(v + 4);
  }
}

// ---- table phase A: per-pair matvec pre-activations (coalesced via Wt) ----
__global__ void k_tabA(const unsigned short* __restrict__ leaf_h8, const float* __restrict__ Wt,
                       float* __restrict__ za) {
  int p = blockIdx.x, t = threadIdx.x;  // 441 x 128
  int tl = p / V_, tr = p % V_;
  __shared__ float hl[128], hr[128];
  hl[t] = bf2f(leaf_h8[tl * H_ + t]);
  hr[t] = bf2f(leaf_h8[tr * H_ + t]);
  __syncthreads();
  float zi = 0.f, zo = 0.f, zu = 0.f, pfl = 0.f, pfr = 0.f;
  for (int k = 0; k < H_; ++k) {
    float l = hl[k], r = hr[k], ht = l + r;
    const float* wr = Wt + k * 512;
    zi = fmaf(ht, wr[t], zi);
    zo = fmaf(ht, wr[128 + t], zo);
    zu = fmaf(ht, wr[256 + t], zu);
    float wf = wr[384 + t];
    pfl = fmaf(l, wf, pfl);
    pfr = fmaf(r, wf, pfr);
  }
  float* z = za + (size_t)p * 640;
  z[t] = zi; z[128 + t] = zo; z[256 + t] = zu; z[384 + t] = pfl; z[512 + t] = pfr;
}

// ---- table phase B: gate epilogue over 22050 rows + idx1 build ----
__global__ void k_tabB(const float* __restrict__ za, const float* __restrict__ symx,
                       const float* __restrict__ leaf_c,
                       const int* __restrict__ tokens, const int* __restrict__ symbols,
                       unsigned short* __restrict__ tab_h8, float* __restrict__ tab_c,
                       int* __restrict__ idx1) {
  int blk = blockIdx.x, t = threadIdx.x;
  if (blk < NTAB / 2) {
    int row = blk * 2 + (t >> 7);
    int u = t & 127;
    int p = row / S_, s = row - p * S_;
    int tl = p / V_, tr = p - tl * V_;
    const float* z = za + (size_t)p * 640;
    const float* sx = symx + (size_t)s * 512;
    float gi = sigm(sx[u] + z[u]);
    float go = sigm(sx[128 + u] + z[128 + u]);
    float gu = tanh_(sx[256 + u] + z[256 + u]);
    float fx = sx[384 + u];
    float fl = sigm(fx + z[384 + u]);
    float fr = sigm(fx + z[512 + u]);
    float cv = fmaf(gi, gu, fmaf(fl, leaf_c[tl * H_ + u], fr * leaf_c[tr * H_ + u]));
    tab_c[(size_t)row * H_ + u] = cv;
    tab_h8[(size_t)row * H_ + u] = f2bf(go * tanh_(cv));
  } else {
    int g = (blk - NTAB / 2) * 256 + t;
    int b = g >> 11, j = g & 2047;
    idx1[g] = (tokens[b * N_ + 2 * j] * V_ + tokens[b * N_ + 2 * j + 1]) * S_ + symbols[b * (N_ - 1) + j];
  }
}

// ---- dense level kernel: 16 nodes/block, 512 threads (8 waves), gate-aligned tiling ----
// Wave w owns col-tiles {w+8g, g=0..3} -> exactly one tile per gate; lane unit cc=16w+cL.
template <bool GATHER>
__global__ void __launch_bounds__(512, 2) k_level(
    const unsigned short* __restrict__ Wfrag, const float* __restrict__ symx,
    const int* __restrict__ symbols, int sym_off, int lgm,
    const unsigned short* __restrict__ h_prev8, const float* __restrict__ c_prev,
    const int* __restrict__ gidx,
    const unsigned short* __restrict__ gh8, const float* __restrict__ gc,
    unsigned short* __restrict__ h_out8, float* __restrict__ c_out) {
  __shared__ __align__(16) unsigned short Asm[32][136];
  int t = threadIdx.x;
  int w = t >> 6, L = t & 63, q = L >> 4, cL = L & 15;
  int g0 = blockIdx.x * 16;

  {  // stage A: 32 rows x 16 int4 = 512 slots
    int row = t >> 4, co = (t & 15) * 8;
    const unsigned short* src = GATHER
        ? gh8 + (size_t)gidx[2 * g0 + row] * H_ + co
        : h_prev8 + (size_t)(2 * g0 + row) * H_ + co;
    *(int4*)&Asm[row][co] = *(const int4*)src;
  }
  __syncthreads();

  f32x4 acc[2][4];
  #pragma unroll
  for (int r = 0; r < 2; ++r)
    #pragma unroll
    for (int g = 0; g < 4; ++g) acc[r][g] = (f32x4){0.f, 0.f, 0.f, 0.f};

  const short8* wf = (const short8*)Wfrag;
  #pragma unroll
  for (int K = 0; K < 4; ++K) {
    short8 bfr[4];
    #pragma unroll
    for (int g = 0; g < 4; ++g) bfr[g] = wf[(size_t)((w + 8 * g) * 4 + K) * 64 + L];
    short8 a0 = *(const short8*)&Asm[cL][K * 32 + q * 8];
    short8 a1 = *(const short8*)&Asm[16 + cL][K * 32 + q * 8];
    #pragma unroll
    for (int g = 0; g < 4; ++g) {
      acc[0][g] = __builtin_amdgcn_mfma_f32_16x16x32_bf16(a0, bfr[g], acc[0][g], 0, 0, 0);
      acc[1][g] = __builtin_amdgcn_mfma_f32_16x16x32_bf16(a1, bfr[g], acc[1][g], 0, 0, 0);
    }
  }

  int cc = 16 * w + cL;
  int mmask = (1 << lgm) - 1;
  #pragma unroll
  for (int r = 0; r < 2; ++r) {
    #pragma unroll
    for (int nd = 0; nd < 2; ++nd) {
      int n = 8 * r + 2 * q + nd;
      int g = g0 + n;
      int bb = g >> lgm, jj = g & mmask;
      int s = symbols[bb * (N_ - 1) + sym_off + jj];
      const float* sx = symx + (size_t)s * 512;
      const float* clp;
      const float* crp;
      if (GATHER) {
        clp = gc + (size_t)gidx[2 * g] * H_;
        crp = gc + (size_t)gidx[2 * g + 1] * H_;
      } else {
        clp = c_prev + (size_t)(2 * g) * H_;
        crp = c_prev + (size_t)(2 * g + 1) * H_;
      }
      float i_p = acc[r][0][2 * nd] + acc[r][0][2 * nd + 1];
      float o_p = acc[r][1][2 * nd] + acc[r][1][2 * nd + 1];
      float u_p = acc[r][2][2 * nd] + acc[r][2][2 * nd + 1];
      float fl_p = acc[r][3][2 * nd];
      float fr_p = acc[r][3][2 * nd + 1];
      float gi = sigm(sx[cc] + i_p);
      float go = sigm(sx[128 + cc] + o_p);
      float gu = tanh_(sx[256 + cc] + u_p);
      float fx = sx[384 + cc];
      float fl = sigm(fx + fl_p);
      float fr = sigm(fx + fr_p);
      float cv = fmaf(gi, gu, fmaf(fl, clp[cc], fr * crp[cc]));
      c_out[(size_t)g * H_ + cc] = cv;
      h_out8[(size_t)g * H_ + cc] = f2bf(go * tanh_(cv));
    }
  }
}

// ---- deep subtree kernel: levels 7-12, one block per batch row, 512 threads ----
__global__ void __launch_bounds__(512, 1) k_deep(
    const unsigned short* __restrict__ Wfrag, const float* __restrict__ symx,
    const int* __restrict__ symbols,
    const unsigned short* __restrict__ in_h8, const float* __restrict__ in_c,
    float* __restrict__ out_root) {
  __shared__ __align__(16) unsigned short Asm[64][136];
  __shared__ float Csm0[64][128];
  __shared__ float Csm1[32][128];
  int t = threadIdx.x;
  int w = t >> 6, L = t & 63, q = L >> 4, cL = L & 15;
  int b = blockIdx.x;

  #pragma unroll
  for (int i = 0; i < 2; ++i) {  // 64 rows x 16 int4
    int fid = t + 512 * i;
    int row = fid >> 4, co = (fid & 15) * 8;
    *(int4*)&Asm[row][co] = *(const int4*)(in_h8 + (size_t)(b * 64 + row) * H_ + co);
  }
  #pragma unroll
  for (int i = 0; i < 4; ++i) {  // 64 rows x 32 float4
    int fid = t + 512 * i;
    int row = fid >> 5, c4 = (fid & 31) << 2;
    *(float4*)&Csm0[row][c4] = *(const float4*)(in_c + (size_t)(b * 64 + row) * H_ + c4);
  }
  __syncthreads();

  const short8* wf = (const short8*)Wfrag;
  int cc = 16 * w + cL;
  int R = 64;
  #pragma unroll
  for (int lev = 0; lev < 6; ++lev) {
    const int l = 7 + lev;
    const int nodes = R >> 1;
    const int jb = b * (N_ - 1) + (N_ - (N_ >> (l - 1)));
    const int nchunk = (R + 31) >> 5;
    for (int c = 0; c < nchunk; ++c) {
      f32x4 acc[2][4];
      #pragma unroll
      for (int r = 0; r < 2; ++r)
        #pragma unroll
        for (int g = 0; g < 4; ++g) acc[r][g] = (f32x4){0.f, 0.f, 0.f, 0.f};
      #pragma unroll
      for (int K = 0; K < 4; ++K) {
        short8 bfr[4];
        #pragma unroll
        for (int g = 0; g < 4; ++g) bfr[g] = wf[(size_t)((w + 8 * g) * 4 + K) * 64 + L];
        short8 a0 = *(const short8*)&Asm[32 * c + cL][K * 32 + q * 8];
        short8 a1 = *(const short8*)&Asm[32 * c + 16 + cL][K * 32 + q * 8];
        #pragma unroll
        for (int g = 0; g < 4; ++g) {
          acc[0][g] = __builtin_amdgcn_mfma_f32_16x16x32_bf16(a0, bfr[g], acc[0][g], 0, 0, 0);
          acc[1][g] = __builtin_amdgcn_mfma_f32_16x16x32_bf16(a1, bfr[g], acc[1][g], 0, 0, 0);
        }
      }
      __syncthreads();  // GEMM reads complete before epilogue writes Asm/Csm
      const float* crd = (l & 1) ? &Csm0[0][0] : &Csm1[0][0];
      float* cwr = (l & 1) ? &Csm1[0][0] : &Csm0[0][0];
      #pragma unroll
      for (int r = 0; r < 2; ++r) {
        #pragma unroll
        for (int nd = 0; nd < 2; ++nd) {
          int n = 16 * c + 8 * r + 2 * q + nd;
          if (n < nodes) {
            int s = symbols[jb + n];
            const float* sx = symx + (size_t)s * 512;
            float i_p = acc[r][0][2 * nd] + acc[r][0][2 * nd + 1];
            float o_p = acc[r][1][2 * nd] + acc[r][1][2 * nd + 1];
            float u_p = acc[r][2][2 * nd] + acc[r][2][2 * nd + 1];
            float fl_p = acc[r][3][2 * nd];
            float fr_p = acc[r][3][2 * nd + 1];
            float gi = sigm(sx[cc] + i_p);
            float go = sigm(sx[128 + cc] + o_p);
            float gu = tanh_(sx[256 + cc] + u_p);
            float fx = sx[384 + cc];
            float fl = sigm(fx + fl_p);
            float fr = sigm(fx + fr_p);
            float cv = fmaf(gi, gu, fmaf(fl, crd[(size_t)(2 * n) * 128 + cc],
                                         fr * crd[(size_t)(2 * n + 1) * 128 + cc]));
            float hv = go * tanh_(cv);
            if (lev == 5) {
              out_root[(size_t)b * H_ + cc] = hv;
            } else {
              cwr[(size_t)n * 128 + cc] = cv;
              Asm[n][cc] = f2bf(hv);
            }
          }
        }
      }
      __syncthreads();
    }
    R >>= 1;
  }
}

// ---- final projection: out = root_h @ Wout.T + bout ----
__global__ void k_out(const float* __restrict__ hroot, const float* __restrict__ Wout,
                      const float* __restrict__ bout, float* __restrict__ out) {
  int b = blockIdx.x, o = threadIdx.x;
  __shared__ float hr[128];
  hr[o] = hroot[(size_t)b * H_ + o];
  __syncthreads();
  float acc = bout[o];
  for (int k = 0; k < H_; ++k) acc = fmaf(hr[k], Wout[o * H_ + k], acc);
  out[(size_t)b * H_ + o] = acc;
}

extern "C" void kernel_launch(void* const* d_in, const int* in_sizes, int n_in,
                              void* d_out, int out_size, void* d_ws, size_t ws_size,
                              hipStream_t stream) {
  const int* tokens    = (const int*)d_in[0];
  const int* symbols   = (const int*)d_in[1];
  const float* emb     = (const float*)d_in[2];
  const float* sym_emb = (const float*)d_in[3];
  const float* Wp  = (const float*)d_in[4];
  const float* bp  = (const float*)d_in[5];
  const float* Wi  = (const float*)d_in[6];
  const float* bi  = (const float*)d_in[7];
  const float* Ui  = (const float*)d_in[8];
  const float* Wf  = (const float*)d_in[9];
  const float* bf  = (const float*)d_in[10];
  const float* Uf  = (const float*)d_in[11];
  const float* Wo  = (const float*)d_in[12];
  const float* bo  = (const float*)d_in[13];
  const float* Uo  = (const float*)d_in[14];
  const float* Wu  = (const float*)d_in[15];
  const float* bu  = (const float*)d_in[16];
  const float* Uu  = (const float*)d_in[17];
  const float* Wout= (const float*)d_in[18];
  const float* bout= (const float*)d_in[19];

  // Workspace (~95 MB)
  char* ws = (char*)d_ws;
  unsigned short* Wfrag   = (unsigned short*)(ws);                // 131072
  float*          Wt      = (float*)(ws + 131072);                // 262144
  unsigned short* leaf_h8 = (unsigned short*)(ws + 393216);       // 5376
  float*          leaf_c  = (float*)(ws + 398592);                // 10752
  float*          symx    = (float*)(ws + 409344);                // 102400
  float*          za      = (float*)(ws + 511744);                // 1128960
  unsigned short* tab_h8  = (unsigned short*)(ws + 1640704);      // 5644800
  float*          tab_c   = (float*)(ws + 7285504UL);             // 11289600
  int*            idx1    = (int*)(ws + 18575104UL);              // 524288
  float*          hroot   = (float*)(ws + 19099392UL);            // 32768
  unsigned short* A_h8    = (unsigned short*)(ws + 19132160UL);   // 65536*128*2 = 16777216
  float*          A_c     = (float*)(ws + 35909376UL);            // 65536*128*4 = 33554432
  unsigned short* B_h8    = (unsigned short*)(ws + 69463808UL);   // 32768*128*2 = 8388608
  float*          B_c     = (float*)(ws + 77852416UL);            // 32768*128*4 = 16777216

  k_pre<<<135, 256, 0, stream>>>(emb, sym_emb, Wp, bp,
      Wi, bi, Ui, Wf, bf, Uf, Wo, bo, Uo, Wu, bu, Uu,
      Wfrag, Wt, leaf_h8, leaf_c, symx);
  k_tabA<<<NPAIR, 128, 0, stream>>>(leaf_h8, Wt, za);
  k_tabB<<<NTAB / 2 + 512, 256, 0, stream>>>(za, symx, leaf_c, tokens, symbols,
      tab_h8, tab_c, idx1);

  // levels 2..6 dense (ping-pong A/B), level 2 gathers from the triple table
  unsigned short* prev_h = nullptr;
  float* prev_c = nullptr;
  int off = 2048;
  for (int l = 2; l <= 6; ++l) {
    int m = N_ >> l;
    int M = B_ * m;
    int lgm = 12 - l;
    unsigned short* oh = (l & 1) ? B_h8 : A_h8;
    float* oc = (l & 1) ? B_c : A_c;
    if (l == 2) {
      k_level<true><<<M / 16, 512, 0, stream>>>(Wfrag, symx, symbols, off, lgm,
          nullptr, nullptr, idx1, tab_h8, tab_c, oh, oc);
    } else {
      k_level<false><<<M / 16, 512, 0, stream>>>(Wfrag, symx, symbols, off, lgm,
          prev_h, prev_c, nullptr, nullptr, nullptr, oh, oc);
    }
    prev_h = oh;
    prev_c = oc;
    off += m;
  }
  // levels 7..12 fused, one block per batch row
  k_deep<<<B_, 512, 0, stream>>>(Wfrag, symx, symbols, prev_h, prev_c, hroot);
  k_out<<<B_, 128, 0, stream>>>(hroot, Wout, bout, (float*)d_out);
}